// Round 1
// baseline (204.821 us; speedup 1.0000x reference)
//
#include <hip/hip_runtime.h>
#include <hip/hip_bf16.h>
#include <stdint.h>
#include <stddef.h>

// ---------- types ----------
typedef __attribute__((ext_vector_type(8))) short bfrag8;   // 8 bf16 in 4 VGPRs
typedef __attribute__((ext_vector_type(4))) float facc4;    // MFMA accumulator

#define SCALING 0.17677669529663687f   // 32^-0.5

__device__ __forceinline__ unsigned short f2bf(float f) {
  union { float f; unsigned u; } v; v.f = f;
  unsigned r = v.u + 0x7fffu + ((v.u >> 16) & 1u);   // RNE
  return (unsigned short)(r >> 16);
}

// ---------------------------------------------------------------------------
// Kernel 1: fp32 -> bf16 convert for query, W_in, W_out
// query: 524288 float4, W_in: 196608, W_out: 65536  => 786432 total, grid 3072
// ---------------------------------------------------------------------------
__global__ __launch_bounds__(256)
void convert_bf16(const float* __restrict__ q, const float* __restrict__ wi,
                  const float* __restrict__ wo,
                  unsigned short* __restrict__ qb, unsigned short* __restrict__ wib,
                  unsigned short* __restrict__ wob) {
  int t = blockIdx.x * 256 + threadIdx.x;
  const float4* src; unsigned short* dst; int idx;
  if (t < 524288)            { src = (const float4*)q;  dst = qb;  idx = t; }
  else if (t < 524288+196608){ src = (const float4*)wi; dst = wib; idx = t - 524288; }
  else                       { src = (const float4*)wo; dst = wob; idx = t - 720896; }
  float4 v = src[idx];
  ushort4 o;
  o.x = f2bf(v.x); o.y = f2bf(v.y); o.z = f2bf(v.z); o.w = f2bf(v.w);
  *(ushort4*)(dst + (size_t)idx * 4) = o;
}

// ---------------------------------------------------------------------------
// Kernel 2/5: GEMM  C[M x N] = A[M x 512] * B[N x 512]^T  (both K-contiguous)
// BM=64, BN=128, BK=32, 256 threads (4 waves in 2x2), wave tile 32x64.
// LDS chunk layout: chunk i = slot*ROWS + row holds 8 bf16 (16B) of (row, k=slot*8..)
//  -> A-frag/B-frag ds_read_b128 lands consecutive rows in consecutive 16B chunks
//     (2-way bank aliasing only, which is free).
// MODE 0: qkv epilogue (+b_in, scale q, scatter to Qs/Ks/V [gh][n][d])
// MODE 1: out epilogue (+b_out, fp32 store to d_out)
// ---------------------------------------------------------------------------
template<int MODE>
__global__ __launch_bounds__(256)
void gemm_bt(const unsigned short* __restrict__ A, const unsigned short* __restrict__ Bw,
             const float* __restrict__ bias,
             unsigned short* __restrict__ oQ, unsigned short* __restrict__ oK,
             unsigned short* __restrict__ oV, float* __restrict__ oF) {
  constexpr int K = 512;
  __shared__ __align__(16) unsigned short lA[2][64 * 32];
  __shared__ __align__(16) unsigned short lB[2][128 * 32];
  const int t = threadIdx.x;
  const int w = t >> 6, l = t & 63;
  const int lr = l & 15, lg = l >> 4;
  const int mBase = blockIdx.x * 64;
  const int nBase = blockIdx.y * 128;
  const int wr = w >> 1, wc = w & 1;

  facc4 acc[2][4];
#pragma unroll
  for (int i = 0; i < 2; i++)
#pragma unroll
    for (int j = 0; j < 4; j++) acc[i][j] = (facc4){0.f, 0.f, 0.f, 0.f};

  // staging source addresses (thread t owns LDS chunk t for A; t and 256+t for B)
  const int arow = t & 63, aslot = t >> 6;
  const unsigned short* aSrc = A + (size_t)(mBase + arow) * K + aslot * 8;
  const int bcol0 = t & 127, bslot0 = t >> 7;
  const int bcol1 = (256 + t) & 127, bslot1 = (256 + t) >> 7;
  const unsigned short* bSrc0 = Bw + (size_t)(nBase + bcol0) * K + bslot0 * 8;
  const unsigned short* bSrc1 = Bw + (size_t)(nBase + bcol1) * K + bslot1 * 8;

  auto stage = [&](int ks, int buf) {
    const int kB = ks * 32;
    *(int4*)(&lA[buf][(size_t)t * 8])         = *(const int4*)(aSrc + kB);
    *(int4*)(&lB[buf][(size_t)t * 8])         = *(const int4*)(bSrc0 + kB);
    *(int4*)(&lB[buf][(size_t)(256 + t) * 8]) = *(const int4*)(bSrc1 + kB);
  };

  stage(0, 0);
  __syncthreads();
#pragma unroll 1
  for (int ks = 0; ks < 16; ks++) {
    const int buf = ks & 1;
    if (ks < 15) stage(ks + 1, buf ^ 1);
    bfrag8 af[2], bfr[4];
#pragma unroll
    for (int qi = 0; qi < 2; qi++)
      af[qi] = *(const bfrag8*)(&lA[buf][(lg * 64 + wr * 32 + qi * 16 + lr) * 8]);
#pragma unroll
    for (int nj = 0; nj < 4; nj++)
      bfr[nj] = *(const bfrag8*)(&lB[buf][(lg * 128 + wc * 64 + nj * 16 + lr) * 8]);
#pragma unroll
    for (int qi = 0; qi < 2; qi++)
#pragma unroll
      for (int nj = 0; nj < 4; nj++)
        acc[qi][nj] = __builtin_amdgcn_mfma_f32_16x16x32_bf16(af[qi], bfr[nj], acc[qi][nj], 0, 0, 0);
    __syncthreads();
  }

  // epilogue: lane holds C[row = base + lg*4 + r][col = base + lr]
#pragma unroll
  for (int qi = 0; qi < 2; qi++)
#pragma unroll
    for (int nj = 0; nj < 4; nj++) {
      int m0 = mBase + wr * 32 + qi * 16 + lg * 4;
      int o = nBase + wc * 64 + nj * 16 + lr;
      float bv = bias[o];
#pragma unroll
      for (int r = 0; r < 4; r++) {
        float v = acc[qi][nj][r] + bv;
        int mm = m0 + r;
        if (MODE == 0) {
          int n = mm >> 2, g = mm & 3;
          int chunk = o >> 9, cc = o & 511, h = cc >> 5, d = cc & 31;
          size_t oidx = ((size_t)(g * 16 + h) * 1024 + n) * 32 + d;
          if (chunk == 0)      oQ[oidx] = f2bf(v * SCALING);
          else if (chunk == 1) oK[oidx] = f2bf(v);
          else                 oV[oidx] = f2bf(v);
        } else {
          oF[(size_t)mm * 512 + o] = v;
        }
      }
    }
}

// ---------------------------------------------------------------------------
// Kernel 3: V [gh][n][32] -> Vt [gh][32][n]   (grid 64 x 4, 256-row tiles)
// ---------------------------------------------------------------------------
__global__ __launch_bounds__(256)
void transpose_v(const unsigned short* __restrict__ V, unsigned short* __restrict__ Vt) {
  __shared__ unsigned short tile[32][264];   // pad keeps 16B alignment (264*2 % 16 == 0)
  const int gh = blockIdx.x, n0 = blockIdx.y * 256;
  const int t = threadIdx.x;
  const unsigned short* src = V + ((size_t)gh * 1024 + n0) * 32;
#pragma unroll
  for (int c = 0; c < 4; c++) {
    int j = c * 256 + t; int row = j >> 2, d0 = (j & 3) * 8;
    bfrag8 v = *(const bfrag8*)(src + (size_t)row * 32 + d0);
#pragma unroll
    for (int i = 0; i < 8; i++) tile[d0 + i][row] = (unsigned short)v[i];
  }
  __syncthreads();
  unsigned short* dst = Vt + (size_t)gh * 32 * 1024 + n0;
#pragma unroll
  for (int c = 0; c < 4; c++) {
    int j = c * 256 + t; int d = j >> 5, n8 = (j & 31) * 8;
    *(bfrag8*)(dst + (size_t)d * 1024 + n8) = *(const bfrag8*)(&tile[d][n8]);
  }
}

// ---------------------------------------------------------------------------
// Kernel 4: fused flash attention with additive bias.
// grid (64 gh, 16 q-tiles of 64), 256 threads = 4 waves, wave owns 16 q-rows.
// K/V read directly from global (L2-resident, 128 KB per gh; same-gh blocks
// share an XCD because gridDim.x=64 and dispatch round-robins x%8).
// Bias: reg-prefetch -> LDS (single buffer, 2 barriers/tile), coalesced float4.
// ---------------------------------------------------------------------------
__global__ __launch_bounds__(256)
void attn_kernel(const unsigned short* __restrict__ Qs, const unsigned short* __restrict__ Ks,
                 const unsigned short* __restrict__ Vt, const float* __restrict__ biasG,
                 unsigned short* __restrict__ Out) {
  constexpr int PAD = 68;
  __shared__ float biasT[64 * PAD];                     // 17.4 KB
  __shared__ __align__(16) unsigned short Pl[4][16 * 64]; // 8 KB, per-wave P tile
  const int gh = blockIdx.x, q0 = blockIdx.y * 64;
  const int t = threadIdx.x, w = t >> 6, l = t & 63;
  const int lr = l & 15, lg = l >> 4;

  const unsigned short* Qg = Qs + (size_t)gh * 1024 * 32;
  const unsigned short* Kg = Ks + (size_t)gh * 1024 * 32;
  const unsigned short* Vg = Vt + (size_t)gh * 32 * 1024;
  const float* Bg = biasG + (size_t)gh * 1024 * 1024 + (size_t)q0 * 1024;

  // Q fragment (row = q0 + w*16 + lr, k = lg*8 .. +8) — held for whole kernel
  bfrag8 qf = *(const bfrag8*)(Qg + (size_t)(q0 + w * 16 + lr) * 32 + lg * 8);

  facc4 accO[2];
  accO[0] = (facc4){0.f, 0.f, 0.f, 0.f};
  accO[1] = (facc4){0.f, 0.f, 0.f, 0.f};
  float mrun[4], lrun[4];
#pragma unroll
  for (int r = 0; r < 4; r++) { mrun[r] = -1e30f; lrun[r] = 0.f; }

  // prologue: stage bias tile 0
  float4 pre[4];
#pragma unroll
  for (int c = 0; c < 4; c++) {
    int idx = c * 256 + t; int row = idx >> 4, c4 = idx & 15;
    pre[c] = *(const float4*)(Bg + (size_t)row * 1024 + c4 * 4);
  }
#pragma unroll
  for (int c = 0; c < 4; c++) {
    int idx = c * 256 + t; int row = idx >> 4, c4 = idx & 15;
    *(float4*)(&biasT[row * PAD + c4 * 4]) = pre[c];
  }
  __syncthreads();

#pragma unroll 1
  for (int kt = 0; kt < 16; kt++) {
    const int kb = kt * 64;
    // prefetch next bias tile into regs (hides HBM latency under compute)
    if (kt < 15) {
#pragma unroll
      for (int c = 0; c < 4; c++) {
        int idx = c * 256 + t; int row = idx >> 4, c4 = idx & 15;
        pre[c] = *(const float4*)(Bg + (size_t)row * 1024 + kb + 64 + c4 * 4);
      }
    }
    // QK^T: 4 column sub-tiles of 16
    facc4 accS[4];
#pragma unroll
    for (int j = 0; j < 4; j++) {
      bfrag8 kf = *(const bfrag8*)(Kg + (size_t)(kb + j * 16 + lr) * 32 + lg * 8);
      facc4 z = (facc4){0.f, 0.f, 0.f, 0.f};
      accS[j] = __builtin_amdgcn_mfma_f32_16x16x32_bf16(qf, kf, z, 0, 0, 0);
    }
    // + bias, row max
    float s[4][4], tm[4];
#pragma unroll
    for (int r = 0; r < 4; r++) tm[r] = -1e30f;
#pragma unroll
    for (int j = 0; j < 4; j++)
#pragma unroll
      for (int r = 0; r < 4; r++) {
        float v = accS[j][r] + biasT[(w * 16 + lg * 4 + r) * PAD + j * 16 + lr];
        s[j][r] = v; tm[r] = fmaxf(tm[r], v);
      }
#pragma unroll
    for (int mk = 1; mk < 16; mk <<= 1)
#pragma unroll
      for (int r = 0; r < 4; r++) tm[r] = fmaxf(tm[r], __shfl_xor(tm[r], mk, 64));
    // online softmax update
    float scale[4];
#pragma unroll
    for (int r = 0; r < 4; r++) {
      float mn = fmaxf(mrun[r], tm[r]);
      scale[r] = __expf(mrun[r] - mn);
      mrun[r] = mn;
    }
    float rs[4] = {0.f, 0.f, 0.f, 0.f};
    unsigned short pb[4][4];
#pragma unroll
    for (int j = 0; j < 4; j++)
#pragma unroll
      for (int r = 0; r < 4; r++) {
        float p = __expf(s[j][r] - mrun[r]);
        rs[r] += p;
        pb[j][r] = f2bf(p);
      }
#pragma unroll
    for (int mk = 1; mk < 16; mk <<= 1)
#pragma unroll
      for (int r = 0; r < 4; r++) rs[r] += __shfl_xor(rs[r], mk, 64);
#pragma unroll
    for (int r = 0; r < 4; r++) lrun[r] = lrun[r] * scale[r] + rs[r];
    // P -> LDS (XOR-swizzled: read side is 16 lanes @ row stride 128B)
    unsigned short* Pw = Pl[w];
#pragma unroll
    for (int j = 0; j < 4; j++)
#pragma unroll
      for (int r = 0; r < 4; r++) {
        int row = lg * 4 + r, col = j * 16 + lr;
        int byte = (row * 128 + col * 2) ^ ((row & 7) << 4);
        *(unsigned short*)((char*)Pw + byte) = pb[j][r];
      }
    // rescale O
#pragma unroll
    for (int h = 0; h < 2; h++)
#pragma unroll
      for (int r = 0; r < 4; r++) accO[h][r] *= scale[r];
    // PV (P A-frags from own-wave LDS; V B-frags 16B-contiguous from Vt)
#pragma unroll
    for (int ksb = 0; ksb < 2; ksb++) {
      int byte = (lr * 128 + (ksb * 32 + lg * 8) * 2) ^ ((lr & 7) << 4);
      bfrag8 pf = *(const bfrag8*)((char*)Pw + byte);
#pragma unroll
      for (int h = 0; h < 2; h++) {
        bfrag8 vf = *(const bfrag8*)(Vg + (size_t)(h * 16 + lr) * 1024 + kb + ksb * 32 + lg * 8);
        accO[h] = __builtin_amdgcn_mfma_f32_16x16x32_bf16(pf, vf, accO[h], 0, 0, 0);
      }
    }
    __syncthreads();           // everyone done reading biasT for tile kt
    if (kt < 15) {
#pragma unroll
      for (int c = 0; c < 4; c++) {
        int idx = c * 256 + t; int row = idx >> 4, c4 = idx & 15;
        *(float4*)(&biasT[row * PAD + c4 * 4]) = pre[c];
      }
    }
    __syncthreads();           // tile kt+1 visible
  }

  // epilogue: O / l  -> attn_out bf16 [4096, 512]
  const int g = gh >> 4, hh = gh & 15;
#pragma unroll
  for (int h = 0; h < 2; h++)
#pragma unroll
    for (int r = 0; r < 4; r++) {
      int q = q0 + w * 16 + lg * 4 + r;
      float v = accO[h][r] / lrun[r];
      int e = hh * 32 + h * 16 + lr;
      Out[(size_t)(q * 4 + g) * 512 + e] = f2bf(v);
    }
}

// ---------------------------------------------------------------------------
extern "C" void kernel_launch(void* const* d_in, const int* in_sizes, int n_in,
                              void* d_out, int out_size, void* d_ws, size_t ws_size,
                              hipStream_t stream) {
  (void)in_sizes; (void)n_in; (void)out_size; (void)ws_size;
  const float* query = (const float*)d_in[0];
  const float* abias = (const float*)d_in[1];
  const float* W_in  = (const float*)d_in[2];
  const float* b_in  = (const float*)d_in[3];
  const float* W_out = (const float*)d_in[4];
  const float* b_out = (const float*)d_in[5];
  float* out = (float*)d_out;
  char* ws = (char*)d_ws;
  unsigned short* qbf  = (unsigned short*)(ws);             // 4 MB
  unsigned short* wibf = (unsigned short*)(ws + 4194304);   // 1.5 MB
  unsigned short* wobf = (unsigned short*)(ws + 5767168);   // 0.5 MB
  unsigned short* Qs   = (unsigned short*)(ws + 6291456);   // 4 MB  [gh][n][d]
  unsigned short* Ks   = (unsigned short*)(ws + 10485760);  // 4 MB  [gh][n][d]
  unsigned short* Vv   = (unsigned short*)(ws + 14680064);  // 4 MB  [gh][n][d]
  unsigned short* Vt   = (unsigned short*)(ws + 18874368);  // 4 MB  [gh][d][n]
  unsigned short* attO = (unsigned short*)(ws + 23068672);  // 4 MB  [m][e]

  convert_bf16<<<3072, 256, 0, stream>>>(query, W_in, W_out, qbf, wibf, wobf);
  gemm_bt<0><<<dim3(64, 12), 256, 0, stream>>>(qbf, wibf, b_in, Qs, Ks, Vv, nullptr);
  transpose_v<<<dim3(64, 4), 256, 0, stream>>>(Vv, Vt);
  attn_kernel<<<dim3(64, 16), 256, 0, stream>>>(Qs, Ks, Vt, abias, attO);
  gemm_bt<1><<<dim3(64, 4), 256, 0, stream>>>(attO, wobf, b_out, nullptr, nullptr, nullptr, out);
}

// Round 2
// 183.240 us; speedup vs baseline: 1.1178x; 1.1178x over previous
//
#include <hip/hip_runtime.h>
#include <hip/hip_bf16.h>
#include <stdint.h>
#include <stddef.h>

// ---------- types ----------
typedef __attribute__((ext_vector_type(8))) short bfrag8;   // 8 bf16 in 4 VGPRs
typedef __attribute__((ext_vector_type(4))) float facc4;    // MFMA accumulator

#define SCALING 0.17677669529663687f   // 32^-0.5

__device__ __forceinline__ unsigned short f2bf(float f) {
  union { float f; unsigned u; } v; v.f = f;
  unsigned r = v.u + 0x7fffu + ((v.u >> 16) & 1u);   // RNE
  return (unsigned short)(r >> 16);
}

// ---------------------------------------------------------------------------
// Kernel 1: fp32 -> bf16 convert for query, W_in, W_out
// ---------------------------------------------------------------------------
__global__ __launch_bounds__(256)
void convert_bf16(const float* __restrict__ q, const float* __restrict__ wi,
                  const float* __restrict__ wo,
                  unsigned short* __restrict__ qb, unsigned short* __restrict__ wib,
                  unsigned short* __restrict__ wob) {
  int t = blockIdx.x * 256 + threadIdx.x;
  const float4* src; unsigned short* dst; int idx;
  if (t < 524288)            { src = (const float4*)q;  dst = qb;  idx = t; }
  else if (t < 524288+196608){ src = (const float4*)wi; dst = wib; idx = t - 524288; }
  else                       { src = (const float4*)wo; dst = wob; idx = t - 720896; }
  float4 v = src[idx];
  ushort4 o;
  o.x = f2bf(v.x); o.y = f2bf(v.y); o.z = f2bf(v.z); o.w = f2bf(v.w);
  *(ushort4*)(dst + (size_t)idx * 4) = o;
}

// ---------------------------------------------------------------------------
// Kernel 2/5: GEMM  C[M x N] = A[M x 512] * B[N x 512]^T  (both K-contiguous)
// BM=64, BN=128, BK=32, 256 threads (4 waves in 2x2), wave tile 32x64.
// __launch_bounds__(256,2): min 2 waves/EU -> 256-VGPR cap. Without the
// min-waves clause the backend targets a ~64-VGPR budget and spills the
// acc/frag set to scratch (round-1 rocprof: 158 MB WRITE_SIZE on attn).
// MODE 0: qkv epilogue (+b_in, scale q, scatter to Qs/Ks/V [gh][n][d])
// MODE 1: out epilogue (+b_out, fp32 store to d_out)
// ---------------------------------------------------------------------------
template<int MODE>
__global__ __launch_bounds__(256, 2)
void gemm_bt(const unsigned short* __restrict__ A, const unsigned short* __restrict__ Bw,
             const float* __restrict__ bias,
             unsigned short* __restrict__ oQ, unsigned short* __restrict__ oK,
             unsigned short* __restrict__ oV, float* __restrict__ oF) {
  constexpr int K = 512;
  __shared__ __align__(16) unsigned short lA[2][64 * 32];
  __shared__ __align__(16) unsigned short lB[2][128 * 32];
  const int t = threadIdx.x;
  const int w = t >> 6, l = t & 63;
  const int lr = l & 15, lg = l >> 4;
  const int mBase = blockIdx.x * 64;
  const int nBase = blockIdx.y * 128;
  const int wr = w >> 1, wc = w & 1;

  facc4 acc[2][4];
#pragma unroll
  for (int i = 0; i < 2; i++)
#pragma unroll
    for (int j = 0; j < 4; j++) acc[i][j] = (facc4){0.f, 0.f, 0.f, 0.f};

  const int arow = t & 63, aslot = t >> 6;
  const unsigned short* aSrc = A + (size_t)(mBase + arow) * K + aslot * 8;
  const int bcol0 = t & 127, bslot0 = t >> 7;
  const int bcol1 = (256 + t) & 127, bslot1 = (256 + t) >> 7;
  const unsigned short* bSrc0 = Bw + (size_t)(nBase + bcol0) * K + bslot0 * 8;
  const unsigned short* bSrc1 = Bw + (size_t)(nBase + bcol1) * K + bslot1 * 8;

  auto stage = [&](int ks, int buf) {
    const int kB = ks * 32;
    *(int4*)(&lA[buf][(size_t)t * 8])         = *(const int4*)(aSrc + kB);
    *(int4*)(&lB[buf][(size_t)t * 8])         = *(const int4*)(bSrc0 + kB);
    *(int4*)(&lB[buf][(size_t)(256 + t) * 8]) = *(const int4*)(bSrc1 + kB);
  };

  stage(0, 0);
  __syncthreads();
#pragma unroll 1
  for (int ks = 0; ks < 16; ks++) {
    const int buf = ks & 1;
    if (ks < 15) stage(ks + 1, buf ^ 1);
    bfrag8 af[2], bfr[4];
#pragma unroll
    for (int qi = 0; qi < 2; qi++)
      af[qi] = *(const bfrag8*)(&lA[buf][(lg * 64 + wr * 32 + qi * 16 + lr) * 8]);
#pragma unroll
    for (int nj = 0; nj < 4; nj++)
      bfr[nj] = *(const bfrag8*)(&lB[buf][(lg * 128 + wc * 64 + nj * 16 + lr) * 8]);
#pragma unroll
    for (int qi = 0; qi < 2; qi++)
#pragma unroll
      for (int nj = 0; nj < 4; nj++)
        acc[qi][nj] = __builtin_amdgcn_mfma_f32_16x16x32_bf16(af[qi], bfr[nj], acc[qi][nj], 0, 0, 0);
    __syncthreads();
  }

#pragma unroll
  for (int qi = 0; qi < 2; qi++)
#pragma unroll
    for (int nj = 0; nj < 4; nj++) {
      int m0 = mBase + wr * 32 + qi * 16 + lg * 4;
      int o = nBase + wc * 64 + nj * 16 + lr;
      float bv = bias[o];
#pragma unroll
      for (int r = 0; r < 4; r++) {
        float v = acc[qi][nj][r] + bv;
        int mm = m0 + r;
        if (MODE == 0) {
          int n = mm >> 2, g = mm & 3;
          int chunk = o >> 9, cc = o & 511, h = cc >> 5, d = cc & 31;
          size_t oidx = ((size_t)(g * 16 + h) * 1024 + n) * 32 + d;
          if (chunk == 0)      oQ[oidx] = f2bf(v * SCALING);
          else if (chunk == 1) oK[oidx] = f2bf(v);
          else                 oV[oidx] = f2bf(v);
        } else {
          oF[(size_t)mm * 512 + o] = v;
        }
      }
    }
}

// ---------------------------------------------------------------------------
// Kernel 3: V [gh][n][32] -> Vt [gh][32][n]   (grid 64 x 4, 256-row tiles)
// ---------------------------------------------------------------------------
__global__ __launch_bounds__(256)
void transpose_v(const unsigned short* __restrict__ V, unsigned short* __restrict__ Vt) {
  __shared__ unsigned short tile[32][264];
  const int gh = blockIdx.x, n0 = blockIdx.y * 256;
  const int t = threadIdx.x;
  const unsigned short* src = V + ((size_t)gh * 1024 + n0) * 32;
#pragma unroll
  for (int c = 0; c < 4; c++) {
    int j = c * 256 + t; int row = j >> 2, d0 = (j & 3) * 8;
    bfrag8 v = *(const bfrag8*)(src + (size_t)row * 32 + d0);
#pragma unroll
    for (int i = 0; i < 8; i++) tile[d0 + i][row] = (unsigned short)v[i];
  }
  __syncthreads();
  unsigned short* dst = Vt + (size_t)gh * 32 * 1024 + n0;
#pragma unroll
  for (int c = 0; c < 4; c++) {
    int j = c * 256 + t; int d = j >> 5, n8 = (j & 31) * 8;
    *(bfrag8*)(dst + (size_t)d * 1024 + n8) = *(const bfrag8*)(&tile[d][n8]);
  }
}

// ---------------------------------------------------------------------------
// Kernel 4: fused flash attention with additive bias.
// grid (64 gh, 16 q-tiles of 64), 256 threads = 4 waves, wave owns 16 q-rows.
// __launch_bounds__(256,2): the ONLY change from round 1. Live set is ~110
// VGPRs (pre[4] float4 + accS/s + accO + softmax state); the default budget
// spilled ~30 regs -> 154 MB of scratch writes per dispatch (rocprof round 1)
// and latency-serialized every iteration. 256-VGPR cap removes all spills;
// HW still fits 3-4 waves/EU at ~110 VGPRs, so occupancy is unchanged or
// better, and the 1-deep bias prefetch becomes sufficient to be BW-bound.
// ---------------------------------------------------------------------------
__global__ __launch_bounds__(256, 2)
void attn_kernel(const unsigned short* __restrict__ Qs, const unsigned short* __restrict__ Ks,
                 const unsigned short* __restrict__ Vt, const float* __restrict__ biasG,
                 unsigned short* __restrict__ Out) {
  constexpr int PAD = 68;
  __shared__ float biasT[64 * PAD];
  __shared__ __align__(16) unsigned short Pl[4][16 * 64];
  const int gh = blockIdx.x, q0 = blockIdx.y * 64;
  const int t = threadIdx.x, w = t >> 6, l = t & 63;
  const int lr = l & 15, lg = l >> 4;

  const unsigned short* Qg = Qs + (size_t)gh * 1024 * 32;
  const unsigned short* Kg = Ks + (size_t)gh * 1024 * 32;
  const unsigned short* Vg = Vt + (size_t)gh * 32 * 1024;
  const float* Bg = biasG + (size_t)gh * 1024 * 1024 + (size_t)q0 * 1024;

  bfrag8 qf = *(const bfrag8*)(Qg + (size_t)(q0 + w * 16 + lr) * 32 + lg * 8);

  facc4 accO[2];
  accO[0] = (facc4){0.f, 0.f, 0.f, 0.f};
  accO[1] = (facc4){0.f, 0.f, 0.f, 0.f};
  float mrun[4], lrun[4];
#pragma unroll
  for (int r = 0; r < 4; r++) { mrun[r] = -1e30f; lrun[r] = 0.f; }

  float4 pre[4];
#pragma unroll
  for (int c = 0; c < 4; c++) {
    int idx = c * 256 + t; int row = idx >> 4, c4 = idx & 15;
    pre[c] = *(const float4*)(Bg + (size_t)row * 1024 + c4 * 4);
  }
#pragma unroll
  for (int c = 0; c < 4; c++) {
    int idx = c * 256 + t; int row = idx >> 4, c4 = idx & 15;
    *(float4*)(&biasT[row * PAD + c4 * 4]) = pre[c];
  }
  __syncthreads();

#pragma unroll 1
  for (int kt = 0; kt < 16; kt++) {
    const int kb = kt * 64;
    if (kt < 15) {
#pragma unroll
      for (int c = 0; c < 4; c++) {
        int idx = c * 256 + t; int row = idx >> 4, c4 = idx & 15;
        pre[c] = *(const float4*)(Bg + (size_t)row * 1024 + kb + 64 + c4 * 4);
      }
    }
    facc4 accS[4];
#pragma unroll
    for (int j = 0; j < 4; j++) {
      bfrag8 kf = *(const bfrag8*)(Kg + (size_t)(kb + j * 16 + lr) * 32 + lg * 8);
      facc4 z = (facc4){0.f, 0.f, 0.f, 0.f};
      accS[j] = __builtin_amdgcn_mfma_f32_16x16x32_bf16(qf, kf, z, 0, 0, 0);
    }
    float s[4][4], tm[4];
#pragma unroll
    for (int r = 0; r < 4; r++) tm[r] = -1e30f;
#pragma unroll
    for (int j = 0; j < 4; j++)
#pragma unroll
      for (int r = 0; r < 4; r++) {
        float v = accS[j][r] + biasT[(w * 16 + lg * 4 + r) * PAD + j * 16 + lr];
        s[j][r] = v; tm[r] = fmaxf(tm[r], v);
      }
#pragma unroll
    for (int mk = 1; mk < 16; mk <<= 1)
#pragma unroll
      for (int r = 0; r < 4; r++) tm[r] = fmaxf(tm[r], __shfl_xor(tm[r], mk, 64));
    float scale[4];
#pragma unroll
    for (int r = 0; r < 4; r++) {
      float mn = fmaxf(mrun[r], tm[r]);
      scale[r] = __expf(mrun[r] - mn);
      mrun[r] = mn;
    }
    float rs[4] = {0.f, 0.f, 0.f, 0.f};
    unsigned short pb[4][4];
#pragma unroll
    for (int j = 0; j < 4; j++)
#pragma unroll
      for (int r = 0; r < 4; r++) {
        float p = __expf(s[j][r] - mrun[r]);
        rs[r] += p;
        pb[j][r] = f2bf(p);
      }
#pragma unroll
    for (int mk = 1; mk < 16; mk <<= 1)
#pragma unroll
      for (int r = 0; r < 4; r++) rs[r] += __shfl_xor(rs[r], mk, 64);
#pragma unroll
    for (int r = 0; r < 4; r++) lrun[r] = lrun[r] * scale[r] + rs[r];
    unsigned short* Pw = Pl[w];
#pragma unroll
    for (int j = 0; j < 4; j++)
#pragma unroll
      for (int r = 0; r < 4; r++) {
        int row = lg * 4 + r, col = j * 16 + lr;
        int byte = (row * 128 + col * 2) ^ ((row & 7) << 4);
        *(unsigned short*)((char*)Pw + byte) = pb[j][r];
      }
#pragma unroll
    for (int h = 0; h < 2; h++)
#pragma unroll
      for (int r = 0; r < 4; r++) accO[h][r] *= scale[r];
#pragma unroll
    for (int ksb = 0; ksb < 2; ksb++) {
      int byte = (lr * 128 + (ksb * 32 + lg * 8) * 2) ^ ((lr & 7) << 4);
      bfrag8 pf = *(const bfrag8*)((char*)Pw + byte);
#pragma unroll
      for (int h = 0; h < 2; h++) {
        bfrag8 vf = *(const bfrag8*)(Vg + (size_t)(h * 16 + lr) * 1024 + kb + ksb * 32 + lg * 8);
        accO[h] = __builtin_amdgcn_mfma_f32_16x16x32_bf16(pf, vf, accO[h], 0, 0, 0);
      }
    }
    __syncthreads();
    if (kt < 15) {
#pragma unroll
      for (int c = 0; c < 4; c++) {
        int idx = c * 256 + t; int row = idx >> 4, c4 = idx & 15;
        *(float4*)(&biasT[row * PAD + c4 * 4]) = pre[c];
      }
    }
    __syncthreads();
  }

  const int g = gh >> 4, hh = gh & 15;
#pragma unroll
  for (int h = 0; h < 2; h++)
#pragma unroll
    for (int r = 0; r < 4; r++) {
      int q = q0 + w * 16 + lg * 4 + r;
      float v = accO[h][r] / lrun[r];
      int e = hh * 32 + h * 16 + lr;
      Out[(size_t)(q * 4 + g) * 512 + e] = f2bf(v);
    }
}

// ---------------------------------------------------------------------------
extern "C" void kernel_launch(void* const* d_in, const int* in_sizes, int n_in,
                              void* d_out, int out_size, void* d_ws, size_t ws_size,
                              hipStream_t stream) {
  (void)in_sizes; (void)n_in; (void)out_size; (void)ws_size;
  const float* query = (const float*)d_in[0];
  const float* abias = (const float*)d_in[1];
  const float* W_in  = (const float*)d_in[2];
  const float* b_in  = (const float*)d_in[3];
  const float* W_out = (const float*)d_in[4];
  const float* b_out = (const float*)d_in[5];
  float* out = (float*)d_out;
  char* ws = (char*)d_ws;
  unsigned short* qbf  = (unsigned short*)(ws);             // 4 MB
  unsigned short* wibf = (unsigned short*)(ws + 4194304);   // 1.5 MB
  unsigned short* wobf = (unsigned short*)(ws + 5767168);   // 0.5 MB
  unsigned short* Qs   = (unsigned short*)(ws + 6291456);   // 4 MB  [gh][n][d]
  unsigned short* Ks   = (unsigned short*)(ws + 10485760);  // 4 MB  [gh][n][d]
  unsigned short* Vv   = (unsigned short*)(ws + 14680064);  // 4 MB  [gh][n][d]
  unsigned short* Vt   = (unsigned short*)(ws + 18874368);  // 4 MB  [gh][d][n]
  unsigned short* attO = (unsigned short*)(ws + 23068672);  // 4 MB  [m][e]

  convert_bf16<<<3072, 256, 0, stream>>>(query, W_in, W_out, qbf, wibf, wobf);
  gemm_bt<0><<<dim3(64, 12), 256, 0, stream>>>(qbf, wibf, b_in, Qs, Ks, Vv, nullptr);
  transpose_v<<<dim3(64, 4), 256, 0, stream>>>(Vv, Vt);
  attn_kernel<<<dim3(64, 16), 256, 0, stream>>>(Qs, Ks, Vt, abias, attO);
  gemm_bt<1><<<dim3(64, 4), 256, 0, stream>>>(attO, wobf, b_out, nullptr, nullptr, nullptr, out);
}

// Round 3
// 122.491 us; speedup vs baseline: 1.6721x; 1.4959x over previous
//
#include <hip/hip_runtime.h>
#include <hip/hip_bf16.h>
#include <stdint.h>
#include <stddef.h>

// ---------- types ----------
typedef __attribute__((ext_vector_type(8))) short bfrag8;   // 8 bf16 in 4 VGPRs
typedef __attribute__((ext_vector_type(4))) float facc4;    // MFMA accumulator

#define SCALING 0.17677669529663687f   // 32^-0.5

__device__ __forceinline__ unsigned short f2bf(float f) {
  union { float f; unsigned u; } v; v.f = f;
  unsigned r = v.u + 0x7fffu + ((v.u >> 16) & 1u);   // RNE
  return (unsigned short)(r >> 16);
}

// ---------------------------------------------------------------------------
// Kernel 1: fp32 -> bf16 convert for query, W_in, W_out
// ---------------------------------------------------------------------------
__global__ __launch_bounds__(256)
void convert_bf16(const float* __restrict__ q, const float* __restrict__ wi,
                  const float* __restrict__ wo,
                  unsigned short* __restrict__ qb, unsigned short* __restrict__ wib,
                  unsigned short* __restrict__ wob) {
  int t = blockIdx.x * 256 + threadIdx.x;
  const float4* src; unsigned short* dst; int idx;
  if (t < 524288)            { src = (const float4*)q;  dst = qb;  idx = t; }
  else if (t < 524288+196608){ src = (const float4*)wi; dst = wib; idx = t - 524288; }
  else                       { src = (const float4*)wo; dst = wob; idx = t - 720896; }
  float4 v = src[idx];
  ushort4 o;
  o.x = f2bf(v.x); o.y = f2bf(v.y); o.z = f2bf(v.z); o.w = f2bf(v.w);
  *(ushort4*)(dst + (size_t)idx * 4) = o;
}

// ---------------------------------------------------------------------------
// Kernel 2/5: GEMM  C[M x N] = A[M x 512] * B[N x 512]^T  (both K-contiguous)
// BM=64, BN=128, BK=32, 256 threads (4 waves in 2x2), wave tile 32x64.
// MODE 0: qkv epilogue (+b_in, scale q, scatter to Qs/Ks/V [gh][n][d])
// MODE 1: out epilogue (+b_out, fp32 store to d_out)
// ---------------------------------------------------------------------------
template<int MODE>
__global__ __launch_bounds__(256, 2)
void gemm_bt(const unsigned short* __restrict__ A, const unsigned short* __restrict__ Bw,
             const float* __restrict__ bias,
             unsigned short* __restrict__ oQ, unsigned short* __restrict__ oK,
             unsigned short* __restrict__ oV, float* __restrict__ oF) {
  constexpr int K = 512;
  __shared__ __align__(16) unsigned short lA[2][64 * 32];
  __shared__ __align__(16) unsigned short lB[2][128 * 32];
  const int t = threadIdx.x;
  const int w = t >> 6, l = t & 63;
  const int lr = l & 15, lg = l >> 4;
  const int mBase = blockIdx.x * 64;
  const int nBase = blockIdx.y * 128;
  const int wr = w >> 1, wc = w & 1;

  facc4 acc[2][4];
#pragma unroll
  for (int i = 0; i < 2; i++)
#pragma unroll
    for (int j = 0; j < 4; j++) acc[i][j] = (facc4){0.f, 0.f, 0.f, 0.f};

  const int arow = t & 63, aslot = t >> 6;
  const unsigned short* aSrc = A + (size_t)(mBase + arow) * K + aslot * 8;
  const int bcol0 = t & 127, bslot0 = t >> 7;
  const int bcol1 = (256 + t) & 127, bslot1 = (256 + t) >> 7;
  const unsigned short* bSrc0 = Bw + (size_t)(nBase + bcol0) * K + bslot0 * 8;
  const unsigned short* bSrc1 = Bw + (size_t)(nBase + bcol1) * K + bslot1 * 8;

  auto stage = [&](int ks, int buf) {
    const int kB = ks * 32;
    *(int4*)(&lA[buf][(size_t)t * 8])         = *(const int4*)(aSrc + kB);
    *(int4*)(&lB[buf][(size_t)t * 8])         = *(const int4*)(bSrc0 + kB);
    *(int4*)(&lB[buf][(size_t)(256 + t) * 8]) = *(const int4*)(bSrc1 + kB);
  };

  stage(0, 0);
  __syncthreads();
#pragma unroll 1
  for (int ks = 0; ks < 16; ks++) {
    const int buf = ks & 1;
    if (ks < 15) stage(ks + 1, buf ^ 1);
    bfrag8 af[2], bfr[4];
#pragma unroll
    for (int qi = 0; qi < 2; qi++)
      af[qi] = *(const bfrag8*)(&lA[buf][(lg * 64 + wr * 32 + qi * 16 + lr) * 8]);
#pragma unroll
    for (int nj = 0; nj < 4; nj++)
      bfr[nj] = *(const bfrag8*)(&lB[buf][(lg * 128 + wc * 64 + nj * 16 + lr) * 8]);
#pragma unroll
    for (int qi = 0; qi < 2; qi++)
#pragma unroll
      for (int nj = 0; nj < 4; nj++)
        acc[qi][nj] = __builtin_amdgcn_mfma_f32_16x16x32_bf16(af[qi], bfr[nj], acc[qi][nj], 0, 0, 0);
    __syncthreads();
  }

#pragma unroll
  for (int qi = 0; qi < 2; qi++)
#pragma unroll
    for (int nj = 0; nj < 4; nj++) {
      int m0 = mBase + wr * 32 + qi * 16 + lg * 4;
      int o = nBase + wc * 64 + nj * 16 + lr;
      float bv = bias[o];
#pragma unroll
      for (int r = 0; r < 4; r++) {
        float v = acc[qi][nj][r] + bv;
        int mm = m0 + r;
        if (MODE == 0) {
          int n = mm >> 2, g = mm & 3;
          int chunk = o >> 9, cc = o & 511, h = cc >> 5, d = cc & 31;
          size_t oidx = ((size_t)(g * 16 + h) * 1024 + n) * 32 + d;
          if (chunk == 0)      oQ[oidx] = f2bf(v * SCALING);
          else if (chunk == 1) oK[oidx] = f2bf(v);
          else                 oV[oidx] = f2bf(v);
        } else {
          oF[(size_t)mm * 512 + o] = v;
        }
      }
    }
}

// ---------------------------------------------------------------------------
// Kernel 3: V [gh][n][32] -> Vt [gh][32][n]   (grid 64 x 4, 256-row tiles)
// ---------------------------------------------------------------------------
__global__ __launch_bounds__(256)
void transpose_v(const unsigned short* __restrict__ V, unsigned short* __restrict__ Vt) {
  __shared__ unsigned short tile[32][264];
  const int gh = blockIdx.x, n0 = blockIdx.y * 256;
  const int t = threadIdx.x;
  const unsigned short* src = V + ((size_t)gh * 1024 + n0) * 32;
#pragma unroll
  for (int c = 0; c < 4; c++) {
    int j = c * 256 + t; int row = j >> 2, d0 = (j & 3) * 8;
    bfrag8 v = *(const bfrag8*)(src + (size_t)row * 32 + d0);
#pragma unroll
    for (int i = 0; i < 8; i++) tile[d0 + i][row] = (unsigned short)v[i];
  }
  __syncthreads();
  unsigned short* dst = Vt + (size_t)gh * 32 * 1024 + n0;
#pragma unroll
  for (int c = 0; c < 4; c++) {
    int j = c * 256 + t; int d = j >> 5, n8 = (j & 31) * 8;
    *(bfrag8*)(dst + (size_t)d * 1024 + n8) = *(const bfrag8*)(&tile[d][n8]);
  }
}

// ---------------------------------------------------------------------------
// Kernel 4: fused flash attention with additive bias — round 3 rewrite.
//
// Round-2 rocprof: 208 MB WRITE_SIZE = register spills (~12 dwords/iter/thread,
// allocator pins a ~64-VGPR budget no matter what launch_bounds says).
// Fix = delete register classes at the source level:
//  * bias has ZERO reuse (each block owns a private 256 KB slice) -> no LDS
//    staging, no pre[] regs, no __syncthreads at all. Read bias directly from
//    global; per-(j,r) wave access = 4 rows x 64 B contiguous segments, fully
//    coalesced at HBM granularity, every byte touched exactly once.
//  * bias dwords are loaded straight into the MFMA C operand (C/D share the
//    same lane->(row,col) layout), so score regs ARE bias regs and the
//    bias-add is done by the matrix pipe for free. Peak live set ~56-60 VGPR.
//  * P tile LDS is per-wave (lgkmcnt-ordered), so the kernel is barrier-free;
//    4 blocks/CU of free-running waves hide bias HBM latency.
// ---------------------------------------------------------------------------
__global__ __launch_bounds__(256)
void attn_kernel(const unsigned short* __restrict__ Qs, const unsigned short* __restrict__ Ks,
                 const unsigned short* __restrict__ Vt, const float* __restrict__ biasG,
                 unsigned short* __restrict__ Out) {
  __shared__ __align__(16) unsigned short Pl[4][16 * 64];   // 8 KB, per-wave P tile
  const int gh = blockIdx.x, q0 = blockIdx.y * 64;
  const int t = threadIdx.x, w = t >> 6, l = t & 63;
  const int lr = l & 15, lg = l >> 4;

  const unsigned short* Qg = Qs + (size_t)gh * 1024 * 32;
  const unsigned short* Kg = Ks + (size_t)gh * 1024 * 32;
  const unsigned short* Vg = Vt + (size_t)gh * 32 * 1024;
  // per-thread bias base: row = q0 + w*16 + lg*4 (+r), col = lr (+j*16 + kb)
  const float* Bt = biasG + (size_t)gh * 1048576 + (size_t)(q0 + w * 16 + lg * 4) * 1024 + lr;

  bfrag8 qf = *(const bfrag8*)(Qg + (size_t)(q0 + w * 16 + lr) * 32 + lg * 8);

  facc4 accO[2];
  accO[0] = (facc4){0.f, 0.f, 0.f, 0.f};
  accO[1] = (facc4){0.f, 0.f, 0.f, 0.f};
  float mrun[4], lrun[4];
#pragma unroll
  for (int r = 0; r < 4; r++) { mrun[r] = -3.0e38f; lrun[r] = 0.f; }

  unsigned short* Pw = Pl[w];

#pragma unroll 1
  for (int kt = 0; kt < 16; kt++) {
    const int kb = kt * 64;
    // bias -> MFMA C operand (16 scalar dword loads, exact consumption layout)
    facc4 sc[4];
#pragma unroll
    for (int j = 0; j < 4; j++)
#pragma unroll
      for (int r = 0; r < 4; r++)
        sc[j][r] = Bt[(size_t)r * 1024 + kb + j * 16];
    // QK^T accumulating onto the bias
#pragma unroll
    for (int j = 0; j < 4; j++) {
      bfrag8 kf = *(const bfrag8*)(Kg + (size_t)(kb + j * 16 + lr) * 32 + lg * 8);
      sc[j] = __builtin_amdgcn_mfma_f32_16x16x32_bf16(qf, kf, sc[j], 0, 0, 0);
    }
    // row max over this tile (16-lane column groups)
    float tm[4];
#pragma unroll
    for (int r = 0; r < 4; r++) tm[r] = -3.0e38f;
#pragma unroll
    for (int j = 0; j < 4; j++)
#pragma unroll
      for (int r = 0; r < 4; r++) tm[r] = fmaxf(tm[r], sc[j][r]);
#pragma unroll
    for (int mk = 1; mk < 16; mk <<= 1)
#pragma unroll
      for (int r = 0; r < 4; r++) tm[r] = fmaxf(tm[r], __shfl_xor(tm[r], mk, 64));
    // online softmax update
    float scale[4];
#pragma unroll
    for (int r = 0; r < 4; r++) {
      float mn = fmaxf(mrun[r], tm[r]);
      scale[r] = __expf(mrun[r] - mn);
      mrun[r] = mn;
    }
    float rs[4] = {0.f, 0.f, 0.f, 0.f};
#pragma unroll
    for (int j = 0; j < 4; j++)
#pragma unroll
      for (int r = 0; r < 4; r++) {
        float p = __expf(sc[j][r] - mrun[r]);
        rs[r] += p;
        int row = lg * 4 + r, col = j * 16 + lr;
        int byte = (row * 128 + col * 2) ^ ((row & 7) << 4);
        *(unsigned short*)((char*)Pw + byte) = f2bf(p);
      }
#pragma unroll
    for (int mk = 1; mk < 16; mk <<= 1)
#pragma unroll
      for (int r = 0; r < 4; r++) rs[r] += __shfl_xor(rs[r], mk, 64);
#pragma unroll
    for (int r = 0; r < 4; r++) lrun[r] = lrun[r] * scale[r] + rs[r];
    // rescale O
#pragma unroll
    for (int h = 0; h < 2; h++)
#pragma unroll
      for (int r = 0; r < 4; r++) accO[h][r] *= scale[r];
    // PV (P A-frags from own-wave LDS; V B-frags 16B-contiguous from Vt)
#pragma unroll
    for (int ksb = 0; ksb < 2; ksb++) {
      int byte = (lr * 128 + (ksb * 32 + lg * 8) * 2) ^ ((lr & 7) << 4);
      bfrag8 pf = *(const bfrag8*)((char*)Pw + byte);
#pragma unroll
      for (int h = 0; h < 2; h++) {
        bfrag8 vf = *(const bfrag8*)(Vg + (size_t)(h * 16 + lr) * 1024 + kb + ksb * 32 + lg * 8);
        accO[h] = __builtin_amdgcn_mfma_f32_16x16x32_bf16(pf, vf, accO[h], 0, 0, 0);
      }
    }
  }

  // epilogue: O / l  -> attn_out bf16 [4096, 512]
  const int g = gh >> 4, hh = gh & 15;
#pragma unroll
  for (int h = 0; h < 2; h++)
#pragma unroll
    for (int r = 0; r < 4; r++) {
      int q = q0 + w * 16 + lg * 4 + r;
      float v = accO[h][r] / lrun[r];
      int e = hh * 32 + h * 16 + lr;
      Out[(size_t)(q * 4 + g) * 512 + e] = f2bf(v);
    }
}

// ---------------------------------------------------------------------------
extern "C" void kernel_launch(void* const* d_in, const int* in_sizes, int n_in,
                              void* d_out, int out_size, void* d_ws, size_t ws_size,
                              hipStream_t stream) {
  (void)in_sizes; (void)n_in; (void)out_size; (void)ws_size;
  const float* query = (const float*)d_in[0];
  const float* abias = (const float*)d_in[1];
  const float* W_in  = (const float*)d_in[2];
  const float* b_in  = (const float*)d_in[3];
  const float* W_out = (const float*)d_in[4];
  const float* b_out = (const float*)d_in[5];
  float* out = (float*)d_out;
  char* ws = (char*)d_ws;
  unsigned short* qbf  = (unsigned short*)(ws);             // 4 MB
  unsigned short* wibf = (unsigned short*)(ws + 4194304);   // 1.5 MB
  unsigned short* wobf = (unsigned short*)(ws + 5767168);   // 0.5 MB
  unsigned short* Qs   = (unsigned short*)(ws + 6291456);   // 4 MB  [gh][n][d]
  unsigned short* Ks   = (unsigned short*)(ws + 10485760);  // 4 MB  [gh][n][d]
  unsigned short* Vv   = (unsigned short*)(ws + 14680064);  // 4 MB  [gh][n][d]
  unsigned short* Vt   = (unsigned short*)(ws + 18874368);  // 4 MB  [gh][d][n]
  unsigned short* attO = (unsigned short*)(ws + 23068672);  // 4 MB  [m][e]

  convert_bf16<<<3072, 256, 0, stream>>>(query, W_in, W_out, qbf, wibf, wobf);
  gemm_bt<0><<<dim3(64, 12), 256, 0, stream>>>(qbf, wibf, b_in, Qs, Ks, Vv, nullptr);
  transpose_v<<<dim3(64, 4), 256, 0, stream>>>(Vv, Vt);
  attn_kernel<<<dim3(64, 16), 256, 0, stream>>>(Qs, Ks, Vt, abias, attO);
  gemm_bt<1><<<dim3(64, 4), 256, 0, stream>>>(attO, wobf, b_out, nullptr, nullptr, nullptr, out);
}